// Round 1
// baseline (367.269 us; speedup 1.0000x reference)
//
#include <hip/hip_runtime.h>
#include <hip/hip_bf16.h>

#define BB 16
#define NN 10
#define CC 128
#define HWD 2304            // 48*48
#define DD (CC*HWD)         // 294912
#define NC (NN*CC)          // 1280
#define CHK 36              // chunks per (b,n) for dot kernel
#define CHUNK (DD/CHK)      // 8192

typedef __bf16 bf16x8 __attribute__((ext_vector_type(8)));
typedef float  f32x4  __attribute__((ext_vector_type(4)));

#define FEAT_BYTES ((size_t)BB*HWD*NC*2)     // 94,371,840
#define WB_BYTES   ((size_t)NC*NC*2)         // 3,276,800
#define PART_FLOATS (BB*NN*CHK*3)            // 17,280

__device__ __forceinline__ ushort f2bf(float f) {
    __hip_bfloat16 h = __float2bfloat16(f);
    return *reinterpret_cast<ushort*>(&h);
}

__device__ __forceinline__ void gload_lds16(const ushort* g, ushort* l) {
    __builtin_amdgcn_global_load_lds(
        (const __attribute__((address_space(1))) void*)(const void*)g,
        (__attribute__((address_space(3))) void*)(void*)l,
        16, 0, 0);
}

// ---------------- Kernel 1: partial dots d0,d1,d2 ----------------
__global__ __launch_bounds__(256) void k_dots(const float* __restrict__ x,
                                              float* __restrict__ part) {
    int blk = blockIdx.x;
    int bn = blk / CHK, ch = blk % CHK;
    int b = bn / NN, n = bn % NN;
    int n1 = (n + 1) % NN, n2 = (n + 2) % NN;
    const float* p0 = x + ((size_t)b*NN + n )*DD + (size_t)ch*CHUNK;
    const float* p1 = x + ((size_t)b*NN + n1)*DD + (size_t)ch*CHUNK;
    const float* p2 = x + ((size_t)b*NN + n2)*DD + (size_t)ch*CHUNK;
    int t = threadIdx.x;
    float s0 = 0.f, s1 = 0.f, s2 = 0.f;
    #pragma unroll
    for (int i = 0; i < CHUNK/1024; ++i) {
        int off = i*1024 + t*4;
        float4 a = *(const float4*)(p0 + off);
        float4 u = *(const float4*)(p1 + off);
        float4 v = *(const float4*)(p2 + off);
        s0 += a.x*a.x + a.y*a.y + a.z*a.z + a.w*a.w;
        s1 += a.x*u.x + a.y*u.y + a.z*u.z + a.w*u.w;
        s2 += a.x*v.x + a.y*v.y + a.z*v.z + a.w*v.w;
    }
    for (int o = 32; o > 0; o >>= 1) {
        s0 += __shfl_down(s0, o);
        s1 += __shfl_down(s1, o);
        s2 += __shfl_down(s2, o);
    }
    __shared__ float red[4][3];
    int w = t >> 6, l = t & 63;
    if (l == 0) { red[w][0] = s0; red[w][1] = s1; red[w][2] = s2; }
    __syncthreads();
    if (t == 0) {
        float r0 = 0.f, r1 = 0.f, r2 = 0.f;
        for (int i = 0; i < 4; ++i) { r0 += red[i][0]; r1 += red[i][1]; r2 += red[i][2]; }
        float* o = part + ((size_t)bn*CHK + ch)*3;
        o[0] = r0; o[1] = r1; o[2] = r2;
    }
}

// ---------------- Kernel 2: softmax -> combination coefficients ----------------
__global__ void k_coef(const float* __restrict__ part,
                       const float* __restrict__ pos_dec,
                       const float* __restrict__ len_dec,
                       float* __restrict__ coef) {
    int bn = threadIdx.x;
    if (bn >= BB*NN) return;
    int n = bn % NN;
    float d0 = 0.f, d1 = 0.f, d2 = 0.f;
    const float* p = part + (size_t)bn*CHK*3;
    for (int i = 0; i < CHK; ++i) { d0 += p[i*3]; d1 += p[i*3+1]; d2 += p[i*3+2]; }
    float pd = pos_dec[n], ld = len_dec[n];
    float l0 = (1.f - pd)*d0 + pd*d1;
    float l1 = ld*((1.f - pd)*d1 + pd*d2);
    float m  = fmaxf(l0, l1);
    float e0 = expf(l0 - m), e1 = expf(l1 - m);
    float inv = 1.f/(e0 + e1);
    float a0 = e0*inv, a1 = e1*inv;
    coef[bn*3+0] = a0*(1.f - pd);
    coef[bn*3+1] = a0*pd + a1*ld*(1.f - pd);
    coef[bn*3+2] = a1*ld*pd;
}

// ---------------- Kernel 3: conv_w fp32 -> bf16 ----------------
__global__ __launch_bounds__(256) void k_wconv(const float* __restrict__ w,
                                               ushort* __restrict__ wb) {
    int i = blockIdx.x*blockDim.x + threadIdx.x;
    size_t idx = (size_t)i*4;
    if (idx >= (size_t)NC*NC) return;
    float4 a = *(const float4*)(w + idx);
    ushort4 o;
    o.x = f2bf(a.x); o.y = f2bf(a.y); o.z = f2bf(a.z); o.w = f2bf(a.w);
    *(ushort4*)(wb + idx) = o;
}

// ---------------- Kernel 4: featT[b][hw][c] bf16 (transposed combo) ----------------
__global__ __launch_bounds__(256) void k_feat(const float* __restrict__ x,
                                              const float* __restrict__ coef,
                                              ushort* __restrict__ featT) {
    __shared__ float tile[32*129];
    int hwt = blockIdx.x;         // 0..71
    int n   = blockIdx.y;         // 0..9
    int b   = blockIdx.z;         // 0..15
    int bn  = b*NN + n;
    float c0 = coef[bn*3+0], c1 = coef[bn*3+1], c2 = coef[bn*3+2];
    int n1 = (n + 1) % NN, n2 = (n + 2) % NN;
    const float* p0 = x + ((size_t)b*NN + n )*DD;
    const float* p1 = x + ((size_t)b*NN + n1)*DD;
    const float* p2 = x + ((size_t)b*NN + n2)*DD;
    int t = threadIdx.x;
    int hw0 = hwt*32;

    // phase 1: read x coalesced (float4 along hw), write LDS [hw][c] (pad 129)
    int ccl = t >> 3;             // 0..31
    int hwi = (t & 7) * 4;        // 0..28
    #pragma unroll
    for (int p = 0; p < 4; ++p) {
        int cc = p*32 + ccl;
        size_t off = (size_t)cc*HWD + hw0 + hwi;
        float4 a = *(const float4*)(p0 + off);
        float4 u = *(const float4*)(p1 + off);
        float4 v = *(const float4*)(p2 + off);
        tile[(hwi+0)*129 + cc] = c0*a.x + c1*u.x + c2*v.x;
        tile[(hwi+1)*129 + cc] = c0*a.y + c1*u.y + c2*v.y;
        tile[(hwi+2)*129 + cc] = c0*a.z + c1*u.z + c2*v.z;
        tile[(hwi+3)*129 + cc] = c0*a.w + c1*u.w + c2*v.w;
    }
    __syncthreads();

    // phase 2: read LDS rows (contiguous c), write featT coalesced (16B/lane)
    int hwl = t >> 4;             // 0..15
    int cc0 = (t & 15) * 8;       // 0..120
    #pragma unroll
    for (int p = 0; p < 2; ++p) {
        int hw = p*16 + hwl;
        const float* src = &tile[hw*129 + cc0];
        union { ushort us[8]; uint4 v; } pk;
        #pragma unroll
        for (int j = 0; j < 8; ++j) pk.us[j] = f2bf(src[j]);
        ushort* dst = featT + (size_t)b*HWD*NC + (size_t)(hw0 + hw)*NC + n*CC + cc0;
        *(uint4*)dst = pk.v;
    }
}

// ---------------- Kernel 5: GEMM out[b,o,hw] = W·featT^T + bias + x ----------------
__global__ __launch_bounds__(256) void k_gemm(const ushort* __restrict__ Wb,
                                              const ushort* __restrict__ featT,
                                              const float* __restrict__ bias,
                                              const float* __restrict__ x,
                                              float* __restrict__ out) {
    __shared__ ushort As[128*32];
    __shared__ ushort Bs[128*32];
    int hwt = blockIdx.x, ot = blockIdx.y, b = blockIdx.z;
    int o0 = ot*128, hw0 = hwt*128;
    int t = threadIdx.x;
    int w = t >> 6, l = t & 63;
    int wr = w >> 1, wc = w & 1;

    const ushort* Ab = Wb + (size_t)o0*NC;
    const ushort* Bb = featT + (size_t)b*HWD*NC + (size_t)hw0*NC;

    f32x4 acc[4][4] = {};

    int srow = l >> 2;            // 0..15 within a 16-row group
    int skc  = (l & 3) * 8;       // k offset 0,8,16,24

    for (int kt = 0; kt < NC/32; ++kt) {
        int k0 = kt*32;
        #pragma unroll
        for (int j = 0; j < 2; ++j) {
            int rg = j*4 + w;     // 16-row group 0..7
            const ushort* ga = Ab + (size_t)(rg*16 + srow)*NC + k0 + skc;
            gload_lds16(ga, &As[rg*512]);
            const ushort* gb = Bb + (size_t)(rg*16 + srow)*NC + k0 + skc;
            gload_lds16(gb, &Bs[rg*512]);
        }
        __syncthreads();

        bf16x8 afr[4], bfr[4];
        #pragma unroll
        for (int m = 0; m < 4; ++m) {
            int row = wr*64 + m*16 + (l & 15);
            afr[m] = *(const bf16x8*)&As[row*32 + (l >> 4)*8];
        }
        #pragma unroll
        for (int n = 0; n < 4; ++n) {
            int row = wc*64 + n*16 + (l & 15);
            bfr[n] = *(const bf16x8*)&Bs[row*32 + (l >> 4)*8];
        }
        #pragma unroll
        for (int m = 0; m < 4; ++m)
            #pragma unroll
            for (int n = 0; n < 4; ++n)
                acc[m][n] = __builtin_amdgcn_mfma_f32_16x16x32_bf16(afr[m], bfr[n], acc[m][n], 0, 0, 0);
        __syncthreads();
    }

    // epilogue: + bias + residual x
    #pragma unroll
    for (int m = 0; m < 4; ++m) {
        int row_o = o0 + wr*64 + m*16 + ((l >> 4) << 2);
        #pragma unroll
        for (int n = 0; n < 4; ++n) {
            int col = hw0 + wc*64 + n*16 + (l & 15);
            #pragma unroll
            for (int r = 0; r < 4; ++r) {
                int ro = row_o + r;
                size_t idx = (size_t)b*NC*HWD + (size_t)ro*HWD + col;
                out[idx] = acc[m][n][r] + bias[ro] + x[idx];
            }
        }
    }
}

extern "C" void kernel_launch(void* const* d_in, const int* in_sizes, int n_in,
                              void* d_out, int out_size, void* d_ws, size_t ws_size,
                              hipStream_t stream) {
    const float* x       = (const float*)d_in[0];
    const float* pos_dec = (const float*)d_in[1];
    const float* len_dec = (const float*)d_in[2];
    const float* conv_w  = (const float*)d_in[3];
    const float* conv_b  = (const float*)d_in[4];
    float* out = (float*)d_out;

    char* ws = (char*)d_ws;
    ushort* featT = (ushort*)ws;                                   // 94,371,840 B
    ushort* wb    = (ushort*)(ws + FEAT_BYTES);                    // 3,276,800 B
    float*  part  = (float*)(ws + FEAT_BYTES + WB_BYTES);          // 69,120 B
    float*  coef  = part + PART_FLOATS;                            // 1,920 B

    k_dots <<<dim3(BB*NN*CHK), 256, 0, stream>>>(x, part);
    k_coef <<<dim3(1), 256, 0, stream>>>(part, pos_dec, len_dec, coef);
    k_wconv<<<dim3(1600), 256, 0, stream>>>(conv_w, wb);
    k_feat <<<dim3(72, NN, BB), 256, 0, stream>>>(x, coef, featT);
    k_gemm <<<dim3(HWD/128, NC/128, BB), 256, 0, stream>>>(wb, featT, conv_b, x, out);
}

// Round 2
// 359.772 us; speedup vs baseline: 1.0208x; 1.0208x over previous
//
#include <hip/hip_runtime.h>
#include <hip/hip_bf16.h>

#define BB 16
#define NN 10
#define CC 128
#define HWD 2304            // 48*48
#define DD (CC*HWD)         // 294912
#define NC (NN*CC)          // 1280
#define CHK 36              // chunks per (b,n) for dot kernel
#define CHUNK (DD/CHK)      // 8192

typedef __bf16 bf16x8 __attribute__((ext_vector_type(8)));
typedef float  f32x4  __attribute__((ext_vector_type(4)));

#define FEAT_BYTES ((size_t)BB*HWD*NC*2)     // 94,371,840
#define WB_BYTES   ((size_t)NC*NC*2)         // 3,276,800
#define PART_FLOATS (BB*NN*CHK*3)            // 17,280

__device__ __forceinline__ ushort f2bf(float f) {
    __hip_bfloat16 h = __float2bfloat16(f);
    return *reinterpret_cast<ushort*>(&h);
}

__device__ __forceinline__ void gload_lds16(const ushort* g, ushort* l) {
    __builtin_amdgcn_global_load_lds(
        (const __attribute__((address_space(1))) void*)(const void*)g,
        (__attribute__((address_space(3))) void*)(void*)l,
        16, 0, 0);
}

// ---------------- Kernel 1: partial dots d0,d1,d2 ----------------
__global__ __launch_bounds__(256) void k_dots(const float* __restrict__ x,
                                              float* __restrict__ part) {
    int blk = blockIdx.x;
    int bn = blk / CHK, ch = blk % CHK;
    int b = bn / NN, n = bn % NN;
    int n1 = (n + 1) % NN, n2 = (n + 2) % NN;
    const float* p0 = x + ((size_t)b*NN + n )*DD + (size_t)ch*CHUNK;
    const float* p1 = x + ((size_t)b*NN + n1)*DD + (size_t)ch*CHUNK;
    const float* p2 = x + ((size_t)b*NN + n2)*DD + (size_t)ch*CHUNK;
    int t = threadIdx.x;
    float s0 = 0.f, s1 = 0.f, s2 = 0.f;
    #pragma unroll
    for (int i = 0; i < CHUNK/1024; ++i) {
        int off = i*1024 + t*4;
        float4 a = *(const float4*)(p0 + off);
        float4 u = *(const float4*)(p1 + off);
        float4 v = *(const float4*)(p2 + off);
        s0 += a.x*a.x + a.y*a.y + a.z*a.z + a.w*a.w;
        s1 += a.x*u.x + a.y*u.y + a.z*u.z + a.w*u.w;
        s2 += a.x*v.x + a.y*v.y + a.z*v.z + a.w*v.w;
    }
    for (int o = 32; o > 0; o >>= 1) {
        s0 += __shfl_down(s0, o);
        s1 += __shfl_down(s1, o);
        s2 += __shfl_down(s2, o);
    }
    __shared__ float red[4][3];
    int w = t >> 6, l = t & 63;
    if (l == 0) { red[w][0] = s0; red[w][1] = s1; red[w][2] = s2; }
    __syncthreads();
    if (t == 0) {
        float r0 = 0.f, r1 = 0.f, r2 = 0.f;
        for (int i = 0; i < 4; ++i) { r0 += red[i][0]; r1 += red[i][1]; r2 += red[i][2]; }
        float* o = part + ((size_t)bn*CHK + ch)*3;
        o[0] = r0; o[1] = r1; o[2] = r2;
    }
}

// ---------------- Kernel 2: softmax -> combination coefficients ----------------
__global__ void k_coef(const float* __restrict__ part,
                       const float* __restrict__ pos_dec,
                       const float* __restrict__ len_dec,
                       float* __restrict__ coef) {
    int bn = threadIdx.x;
    if (bn >= BB*NN) return;
    int n = bn % NN;
    float d0 = 0.f, d1 = 0.f, d2 = 0.f;
    const float* p = part + (size_t)bn*CHK*3;
    for (int i = 0; i < CHK; ++i) { d0 += p[i*3]; d1 += p[i*3+1]; d2 += p[i*3+2]; }
    float pd = pos_dec[n], ld = len_dec[n];
    float l0 = (1.f - pd)*d0 + pd*d1;
    float l1 = ld*((1.f - pd)*d1 + pd*d2);
    float m  = fmaxf(l0, l1);
    float e0 = expf(l0 - m), e1 = expf(l1 - m);
    float inv = 1.f/(e0 + e1);
    float a0 = e0*inv, a1 = e1*inv;
    coef[bn*3+0] = a0*(1.f - pd);
    coef[bn*3+1] = a0*pd + a1*ld*(1.f - pd);
    coef[bn*3+2] = a1*ld*pd;
}

// ---------------- Kernel 3: conv_w fp32 -> bf16 ----------------
__global__ __launch_bounds__(256) void k_wconv(const float* __restrict__ w,
                                               ushort* __restrict__ wb) {
    int i = blockIdx.x*blockDim.x + threadIdx.x;
    size_t idx = (size_t)i*4;
    if (idx >= (size_t)NC*NC) return;
    float4 a = *(const float4*)(w + idx);
    ushort4 o;
    o.x = f2bf(a.x); o.y = f2bf(a.y); o.z = f2bf(a.z); o.w = f2bf(a.w);
    *(ushort4*)(wb + idx) = o;
}

// ---------------- Kernel 4: featT[b][hw][c] bf16 (transposed combo) ----------------
__global__ __launch_bounds__(256) void k_feat(const float* __restrict__ x,
                                              const float* __restrict__ coef,
                                              ushort* __restrict__ featT) {
    __shared__ float tile[32*129];
    int hwt = blockIdx.x;         // 0..71
    int n   = blockIdx.y;         // 0..9
    int b   = blockIdx.z;         // 0..15
    int bn  = b*NN + n;
    float c0 = coef[bn*3+0], c1 = coef[bn*3+1], c2 = coef[bn*3+2];
    int n1 = (n + 1) % NN, n2 = (n + 2) % NN;
    const float* p0 = x + ((size_t)b*NN + n )*DD;
    const float* p1 = x + ((size_t)b*NN + n1)*DD;
    const float* p2 = x + ((size_t)b*NN + n2)*DD;
    int t = threadIdx.x;
    int hw0 = hwt*32;

    // phase 1: read x coalesced (float4 along hw), write LDS [hw][c] (pad 129)
    int ccl = t >> 3;             // 0..31
    int hwi = (t & 7) * 4;        // 0..28
    #pragma unroll
    for (int p = 0; p < 4; ++p) {
        int cc = p*32 + ccl;
        size_t off = (size_t)cc*HWD + hw0 + hwi;
        float4 a = *(const float4*)(p0 + off);
        float4 u = *(const float4*)(p1 + off);
        float4 v = *(const float4*)(p2 + off);
        tile[(hwi+0)*129 + cc] = c0*a.x + c1*u.x + c2*v.x;
        tile[(hwi+1)*129 + cc] = c0*a.y + c1*u.y + c2*v.y;
        tile[(hwi+2)*129 + cc] = c0*a.z + c1*u.z + c2*v.z;
        tile[(hwi+3)*129 + cc] = c0*a.w + c1*u.w + c2*v.w;
    }
    __syncthreads();

    // phase 2: read LDS rows (contiguous c), write featT coalesced (16B/lane)
    int hwl = t >> 4;             // 0..15
    int cc0 = (t & 15) * 8;       // 0..120
    #pragma unroll
    for (int p = 0; p < 2; ++p) {
        int hw = p*16 + hwl;
        const float* src = &tile[hw*129 + cc0];
        union { ushort us[8]; uint4 v; } pk;
        #pragma unroll
        for (int j = 0; j < 8; ++j) pk.us[j] = f2bf(src[j]);
        ushort* dst = featT + (size_t)b*HWD*NC + (size_t)(hw0 + hw)*NC + n*CC + cc0;
        *(uint4*)dst = pk.v;
    }
}

// ---------------- Kernel 5: GEMM out[b,o,hw] = W·featT^T + bias + x ----------------
// LDS tiles are [128 rows][32 k] ushort, stored with chunk-swizzle:
//   physical 16B-chunk index = logical_chunk ^ ((row>>1)&3)
// Staging keeps the LDS destination LINEAR (global_load_lds requirement) and
// pre-swizzles the GLOBAL source k-chunk; reads apply the same involution.
__global__ __launch_bounds__(256) void k_gemm(const ushort* __restrict__ Wb,
                                              const ushort* __restrict__ featT,
                                              const float* __restrict__ bias,
                                              const float* __restrict__ x,
                                              float* __restrict__ out) {
    __shared__ ushort As[128*32];
    __shared__ ushort Bs[128*32];
    int hwt = blockIdx.x, ot = blockIdx.y, b = blockIdx.z;
    int o0 = ot*128, hw0 = hwt*128;
    int t = threadIdx.x;
    int w = t >> 6, l = t & 63;
    int wr = w >> 1, wc = w & 1;

    const ushort* Ab = Wb + (size_t)o0*NC;
    const ushort* Bb = featT + (size_t)b*HWD*NC + (size_t)hw0*NC;

    f32x4 acc[4][4] = {};

    int srow = l >> 2;                            // 0..15 within a 16-row group
    int skc  = ((l & 3) ^ ((l >> 3) & 3)) * 8;    // pre-swizzled global k-chunk
    int ksw  = (((l >> 4) ^ ((l >> 1) & 3))) * 8; // swizzled read k-offset

    for (int kt = 0; kt < NC/32; ++kt) {
        int k0 = kt*32;
        #pragma unroll
        for (int j = 0; j < 2; ++j) {
            int rg = j*4 + w;     // 16-row group 0..7
            const ushort* ga = Ab + (size_t)(rg*16 + srow)*NC + k0 + skc;
            gload_lds16(ga, &As[rg*512]);
            const ushort* gb = Bb + (size_t)(rg*16 + srow)*NC + k0 + skc;
            gload_lds16(gb, &Bs[rg*512]);
        }
        __syncthreads();

        bf16x8 afr[4], bfr[4];
        #pragma unroll
        for (int m = 0; m < 4; ++m) {
            int row = wr*64 + m*16 + (l & 15);
            afr[m] = *(const bf16x8*)&As[row*32 + ksw];
        }
        #pragma unroll
        for (int n = 0; n < 4; ++n) {
            int row = wc*64 + n*16 + (l & 15);
            bfr[n] = *(const bf16x8*)&Bs[row*32 + ksw];
        }
        #pragma unroll
        for (int m = 0; m < 4; ++m)
            #pragma unroll
            for (int n = 0; n < 4; ++n)
                acc[m][n] = __builtin_amdgcn_mfma_f32_16x16x32_bf16(afr[m], bfr[n], acc[m][n], 0, 0, 0);
        __syncthreads();
    }

    // epilogue: + bias + residual x
    #pragma unroll
    for (int m = 0; m < 4; ++m) {
        int row_o = o0 + wr*64 + m*16 + ((l >> 4) << 2);
        #pragma unroll
        for (int n = 0; n < 4; ++n) {
            int col = hw0 + wc*64 + n*16 + (l & 15);
            #pragma unroll
            for (int r = 0; r < 4; ++r) {
                int ro = row_o + r;
                size_t idx = (size_t)b*NC*HWD + (size_t)ro*HWD + col;
                out[idx] = acc[m][n][r] + bias[ro] + x[idx];
            }
        }
    }
}

extern "C" void kernel_launch(void* const* d_in, const int* in_sizes, int n_in,
                              void* d_out, int out_size, void* d_ws, size_t ws_size,
                              hipStream_t stream) {
    const float* x       = (const float*)d_in[0];
    const float* pos_dec = (const float*)d_in[1];
    const float* len_dec = (const float*)d_in[2];
    const float* conv_w  = (const float*)d_in[3];
    const float* conv_b  = (const float*)d_in[4];
    float* out = (float*)d_out;

    char* ws = (char*)d_ws;
    ushort* featT = (ushort*)ws;                                   // 94,371,840 B
    ushort* wb    = (ushort*)(ws + FEAT_BYTES);                    // 3,276,800 B
    float*  part  = (float*)(ws + FEAT_BYTES + WB_BYTES);          // 69,120 B
    float*  coef  = part + PART_FLOATS;                            // 1,920 B

    k_dots <<<dim3(BB*NN*CHK), 256, 0, stream>>>(x, part);
    k_coef <<<dim3(1), 256, 0, stream>>>(part, pos_dec, len_dec, coef);
    k_wconv<<<dim3(1600), 256, 0, stream>>>(conv_w, wb);
    k_feat <<<dim3(72, NN, BB), 256, 0, stream>>>(x, coef, featT);
    k_gemm <<<dim3(HWD/128, NC/128, BB), 256, 0, stream>>>(wb, featT, conv_b, x, out);
}

// Round 3
// 322.429 us; speedup vs baseline: 1.1391x; 1.1158x over previous
//
#include <hip/hip_runtime.h>
#include <hip/hip_bf16.h>

#define BB 16
#define NN 10
#define CC 128
#define HWD 2304            // 48*48
#define DD (CC*HWD)         // 294912
#define NC (NN*CC)          // 1280
#define CHK 36              // chunks per (b,n) for dot kernel
#define CHUNK (DD/CHK)      // 8192

#define BM 256
#define BN 256
#define BK 64
#define TK (NC/BK)          // 20 K-tiles

typedef __bf16 bf16x8 __attribute__((ext_vector_type(8)));
typedef float  f32x4  __attribute__((ext_vector_type(4)));

#define FEAT_BYTES ((size_t)BB*HWD*NC*2)     // 94,371,840
#define WB_BYTES   ((size_t)NC*NC*2)         // 3,276,800
#define PART_FLOATS (BB*NN*CHK*3)            // 17,280

__device__ __forceinline__ ushort f2bf(float f) {
    __hip_bfloat16 h = __float2bfloat16(f);
    return *reinterpret_cast<ushort*>(&h);
}

__device__ __forceinline__ void gload_lds16(const ushort* g, ushort* l) {
    __builtin_amdgcn_global_load_lds(
        (const __attribute__((address_space(1))) void*)(const void*)g,
        (__attribute__((address_space(3))) void*)(void*)l,
        16, 0, 0);
}

// ---------------- Kernel 1: partial dots d0,d1,d2 ----------------
__global__ __launch_bounds__(256) void k_dots(const float* __restrict__ x,
                                              float* __restrict__ part) {
    int blk = blockIdx.x;
    int bn = blk / CHK, ch = blk % CHK;
    int b = bn / NN, n = bn % NN;
    int n1 = (n + 1) % NN, n2 = (n + 2) % NN;
    const float* p0 = x + ((size_t)b*NN + n )*DD + (size_t)ch*CHUNK;
    const float* p1 = x + ((size_t)b*NN + n1)*DD + (size_t)ch*CHUNK;
    const float* p2 = x + ((size_t)b*NN + n2)*DD + (size_t)ch*CHUNK;
    int t = threadIdx.x;
    float s0 = 0.f, s1 = 0.f, s2 = 0.f;
    #pragma unroll
    for (int i = 0; i < CHUNK/1024; ++i) {
        int off = i*1024 + t*4;
        float4 a = *(const float4*)(p0 + off);
        float4 u = *(const float4*)(p1 + off);
        float4 v = *(const float4*)(p2 + off);
        s0 += a.x*a.x + a.y*a.y + a.z*a.z + a.w*a.w;
        s1 += a.x*u.x + a.y*u.y + a.z*u.z + a.w*u.w;
        s2 += a.x*v.x + a.y*v.y + a.z*v.z + a.w*v.w;
    }
    for (int o = 32; o > 0; o >>= 1) {
        s0 += __shfl_down(s0, o);
        s1 += __shfl_down(s1, o);
        s2 += __shfl_down(s2, o);
    }
    __shared__ float red[4][3];
    int w = t >> 6, l = t & 63;
    if (l == 0) { red[w][0] = s0; red[w][1] = s1; red[w][2] = s2; }
    __syncthreads();
    if (t == 0) {
        float r0 = 0.f, r1 = 0.f, r2 = 0.f;
        for (int i = 0; i < 4; ++i) { r0 += red[i][0]; r1 += red[i][1]; r2 += red[i][2]; }
        float* o = part + ((size_t)bn*CHK + ch)*3;
        o[0] = r0; o[1] = r1; o[2] = r2;
    }
}

// ---------------- Kernel 2: softmax -> combination coefficients ----------------
__global__ void k_coef(const float* __restrict__ part,
                       const float* __restrict__ pos_dec,
                       const float* __restrict__ len_dec,
                       float* __restrict__ coef) {
    int bn = threadIdx.x;
    if (bn >= BB*NN) return;
    int n = bn % NN;
    float d0 = 0.f, d1 = 0.f, d2 = 0.f;
    const float* p = part + (size_t)bn*CHK*3;
    for (int i = 0; i < CHK; ++i) { d0 += p[i*3]; d1 += p[i*3+1]; d2 += p[i*3+2]; }
    float pd = pos_dec[n], ld = len_dec[n];
    float l0 = (1.f - pd)*d0 + pd*d1;
    float l1 = ld*((1.f - pd)*d1 + pd*d2);
    float m  = fmaxf(l0, l1);
    float e0 = expf(l0 - m), e1 = expf(l1 - m);
    float inv = 1.f/(e0 + e1);
    float a0 = e0*inv, a1 = e1*inv;
    coef[bn*3+0] = a0*(1.f - pd);
    coef[bn*3+1] = a0*pd + a1*ld*(1.f - pd);
    coef[bn*3+2] = a1*ld*pd;
}

// ---------------- Kernel 3: conv_w fp32 -> bf16 ----------------
__global__ __launch_bounds__(256) void k_wconv(const float* __restrict__ w,
                                               ushort* __restrict__ wb) {
    int i = blockIdx.x*blockDim.x + threadIdx.x;
    size_t idx = (size_t)i*4;
    if (idx >= (size_t)NC*NC) return;
    float4 a = *(const float4*)(w + idx);
    ushort4 o;
    o.x = f2bf(a.x); o.y = f2bf(a.y); o.z = f2bf(a.z); o.w = f2bf(a.w);
    *(ushort4*)(wb + idx) = o;
}

// ---------------- Kernel 4: featT[b][hw][c] bf16 (transposed combo) ----------------
__global__ __launch_bounds__(256) void k_feat(const float* __restrict__ x,
                                              const float* __restrict__ coef,
                                              ushort* __restrict__ featT) {
    __shared__ float tile[32*129];
    int hwt = blockIdx.x;         // 0..71
    int n   = blockIdx.y;         // 0..9
    int b   = blockIdx.z;         // 0..15
    int bn  = b*NN + n;
    float c0 = coef[bn*3+0], c1 = coef[bn*3+1], c2 = coef[bn*3+2];
    int n1 = (n + 1) % NN, n2 = (n + 2) % NN;
    const float* p0 = x + ((size_t)b*NN + n )*DD;
    const float* p1 = x + ((size_t)b*NN + n1)*DD;
    const float* p2 = x + ((size_t)b*NN + n2)*DD;
    int t = threadIdx.x;
    int hw0 = hwt*32;

    int ccl = t >> 3;             // 0..31
    int hwi = (t & 7) * 4;        // 0..28
    #pragma unroll
    for (int p = 0; p < 4; ++p) {
        int cc = p*32 + ccl;
        size_t off = (size_t)cc*HWD + hw0 + hwi;
        float4 a = *(const float4*)(p0 + off);
        float4 u = *(const float4*)(p1 + off);
        float4 v = *(const float4*)(p2 + off);
        tile[(hwi+0)*129 + cc] = c0*a.x + c1*u.x + c2*v.x;
        tile[(hwi+1)*129 + cc] = c0*a.y + c1*u.y + c2*v.y;
        tile[(hwi+2)*129 + cc] = c0*a.z + c1*u.z + c2*v.z;
        tile[(hwi+3)*129 + cc] = c0*a.w + c1*u.w + c2*v.w;
    }
    __syncthreads();

    int hwl = t >> 4;             // 0..15
    int cc0 = (t & 15) * 8;       // 0..120
    #pragma unroll
    for (int p = 0; p < 2; ++p) {
        int hw = p*16 + hwl;
        const float* src = &tile[hw*129 + cc0];
        union { ushort us[8]; uint4 v; } pk;
        #pragma unroll
        for (int j = 0; j < 8; ++j) pk.us[j] = f2bf(src[j]);
        ushort* dst = featT + (size_t)b*HWD*NC + (size_t)(hw0 + hw)*NC + n*CC + cc0;
        *(uint4*)dst = pk.v;
    }
}

// ---------------- Kernel 5: 256x256x64 double-buffered GEMM, counted vmcnt ----------------
// LDS logical layout [256 rows][8 chunks of 16B], physical chunk = logical ^ (row&7).
// Staging keeps LDS dest LINEAR (gload_lds), pre-swizzles the GLOBAL k-chunk.
__device__ __forceinline__ void stage_tile(const ushort* __restrict__ Ag,
                                           const ushort* __restrict__ Bg,
                                           ushort* as, ushort* bs,
                                           int t, int kO) {
    int r  = t >> 3;                      // 0..63 (row within 64-row pass)
    int kc = ((t & 7) ^ (r & 7)) * 8;     // pre-swizzled k-chunk (ushorts)
    #pragma unroll
    for (int p = 0; p < 4; ++p)
        gload_lds16(Ag + (size_t)(p*64 + r)*NC + kO + kc, as + p*4096 + t*8);
    #pragma unroll
    for (int p = 0; p < 4; ++p)
        gload_lds16(Bg + (size_t)(p*64 + r)*NC + kO + kc, bs + p*4096 + t*8);
}

__global__ __launch_bounds__(512, 2) void k_gemm(const ushort* __restrict__ Wb,
                                                 const ushort* __restrict__ featT,
                                                 const float* __restrict__ bias,
                                                 const float* __restrict__ x,
                                                 float* __restrict__ out) {
    __shared__ ushort As[2][BM*BK];   // 2 x 32 KiB
    __shared__ ushort Bs[2][BN*BK];   // 2 x 32 KiB

    // bijective XCD swizzle: 720 blocks, 90 per XCD; consecutive work ids
    // (5 o-tiles sharing one featT panel) land on the same XCD.
    int bid = blockIdx.x;
    int wkid = (bid & 7) * 90 + (bid >> 3);
    int b   = wkid / 45;
    int r45 = wkid % 45;
    int hwt = r45 / 5;
    int ot  = r45 % 5;
    int o0 = ot*BM, hw0 = hwt*BN;

    int t = threadIdx.x;
    int l = t & 63;
    int w = t >> 6;
    int wr = w >> 2, wc = w & 3;      // 2 x 4 wave grid

    const ushort* Ag = Wb + (size_t)o0*NC;
    const ushort* Bg = featT + (size_t)b*HWD*NC + (size_t)hw0*NC;

    int rowA = wr*128 + (l & 15);
    int rowB = wc*64  + (l & 15);
    int cA   = l >> 4;                // 0..3
    int xr   = l & 7;                 // swizzle bits

    f32x4 acc[8][4] = {};

    // prologue: stage tiles 0 and 1
    stage_tile(Ag, Bg, As[0], Bs[0], t, 0);
    stage_tile(Ag, Bg, As[1], Bs[1], t, BK);
    asm volatile("s_waitcnt vmcnt(8)" ::: "memory");   // tile 0 complete
    __builtin_amdgcn_s_barrier();
    __builtin_amdgcn_sched_barrier(0);

    for (int kt = 0; kt < TK; ++kt) {
        int cur = kt & 1;
        const ushort* as = As[cur];
        const ushort* bs = Bs[cur];

        #pragma unroll
        for (int kq = 0; kq < 2; ++kq) {
            bf16x8 bfr[4];
            #pragma unroll
            for (int n = 0; n < 4; ++n)
                bfr[n] = *(const bf16x8*)&bs[(rowB + n*16)*BK + ((((kq<<2)|cA) ^ xr)<<3)];
            #pragma unroll
            for (int mq = 0; mq < 2; ++mq) {
                bf16x8 afr[4];
                #pragma unroll
                for (int i = 0; i < 4; ++i)
                    afr[i] = *(const bf16x8*)&as[(rowA + mq*64 + i*16)*BK + ((((kq<<2)|cA) ^ xr)<<3)];
                __builtin_amdgcn_s_setprio(1);
                #pragma unroll
                for (int i = 0; i < 4; ++i)
                    #pragma unroll
                    for (int n = 0; n < 4; ++n)
                        acc[mq*4+i][n] = __builtin_amdgcn_mfma_f32_16x16x32_bf16(
                            afr[i], bfr[n], acc[mq*4+i][n], 0, 0, 0);
                __builtin_amdgcn_s_setprio(0);
            }
        }

        // all our reads of buf[cur] are consumed (compiler waits lgkm before MFMA)
        asm volatile("" ::: "memory");
        __builtin_amdgcn_s_barrier();          // everyone done reading buf[cur]
        __builtin_amdgcn_sched_barrier(0);

        if (kt + 2 < TK) {
            stage_tile(Ag, Bg, As[cur], Bs[cur], t, (kt+2)*BK);
            asm volatile("s_waitcnt vmcnt(8)" ::: "memory");  // tile kt+1 done, kt+2 in flight
        } else {
            asm volatile("s_waitcnt vmcnt(0)" ::: "memory");  // drain tail
        }
        __builtin_amdgcn_s_barrier();          // tile kt+1 visible to all waves
        __builtin_amdgcn_sched_barrier(0);
    }

    // epilogue: + bias + residual x
    #pragma unroll
    for (int m = 0; m < 8; ++m) {
        int ro_base = o0 + wr*128 + m*16 + ((l >> 4) << 2);
        #pragma unroll
        for (int n = 0; n < 4; ++n) {
            int col = hw0 + wc*64 + n*16 + (l & 15);
            #pragma unroll
            for (int r = 0; r < 4; ++r) {
                int ro = ro_base + r;
                size_t idx = (size_t)b*NC*HWD + (size_t)ro*HWD + col;
                out[idx] = acc[m][n][r] + bias[ro] + x[idx];
            }
        }
    }
}

extern "C" void kernel_launch(void* const* d_in, const int* in_sizes, int n_in,
                              void* d_out, int out_size, void* d_ws, size_t ws_size,
                              hipStream_t stream) {
    const float* x       = (const float*)d_in[0];
    const float* pos_dec = (const float*)d_in[1];
    const float* len_dec = (const float*)d_in[2];
    const float* conv_w  = (const float*)d_in[3];
    const float* conv_b  = (const float*)d_in[4];
    float* out = (float*)d_out;

    char* ws = (char*)d_ws;
    ushort* featT = (ushort*)ws;                                   // 94,371,840 B
    ushort* wb    = (ushort*)(ws + FEAT_BYTES);                    // 3,276,800 B
    float*  part  = (float*)(ws + FEAT_BYTES + WB_BYTES);          // 69,120 B
    float*  coef  = part + PART_FLOATS;                            // 1,920 B

    k_dots <<<dim3(BB*NN*CHK), 256, 0, stream>>>(x, part);
    k_coef <<<dim3(1), 256, 0, stream>>>(part, pos_dec, len_dec, coef);
    k_wconv<<<dim3(1600), 256, 0, stream>>>(conv_w, wb);
    k_feat <<<dim3(72, NN, BB), 256, 0, stream>>>(x, coef, featT);
    k_gemm <<<dim3(720), 512, 0, stream>>>(wb, featT, conv_b, x, out);
}

// Round 4
// 305.803 us; speedup vs baseline: 1.2010x; 1.0544x over previous
//
#include <hip/hip_runtime.h>
#include <hip/hip_bf16.h>

#define BB 16
#define NN 10
#define CC 128
#define HWD 2304            // 48*48
#define DD (CC*HWD)         // 294912
#define NC (NN*CC)          // 1280
#define CHK 36              // chunks per (b,n) for dot kernel
#define CHUNK (DD/CHK)      // 8192

#define BM 256
#define BN 256
#define BK2 32              // half-K-tile
#define NHALF (NC/BK2)      // 40 half-tiles

typedef __bf16 bf16x8 __attribute__((ext_vector_type(8)));
typedef float  f32x4  __attribute__((ext_vector_type(4)));

#define FEAT_BYTES ((size_t)BB*HWD*NC*2)     // 94,371,840
#define WB_BYTES   ((size_t)NC*NC*2)         // 3,276,800
#define PART_FLOATS (BB*NN*CHK*3)            // 17,280

__device__ __forceinline__ ushort f2bf(float f) {
    __hip_bfloat16 h = __float2bfloat16(f);
    return *reinterpret_cast<ushort*>(&h);
}

__device__ __forceinline__ void gload_lds16(const ushort* g, ushort* l) {
    __builtin_amdgcn_global_load_lds(
        (const __attribute__((address_space(1))) void*)(const void*)g,
        (__attribute__((address_space(3))) void*)(void*)l,
        16, 0, 0);
}

// ---------------- Kernel 1: partial dots d0,d1,d2 ----------------
__global__ __launch_bounds__(256) void k_dots(const float* __restrict__ x,
                                              float* __restrict__ part) {
    int blk = blockIdx.x;
    int bn = blk / CHK, ch = blk % CHK;
    int b = bn / NN, n = bn % NN;
    int n1 = (n + 1) % NN, n2 = (n + 2) % NN;
    const float* p0 = x + ((size_t)b*NN + n )*DD + (size_t)ch*CHUNK;
    const float* p1 = x + ((size_t)b*NN + n1)*DD + (size_t)ch*CHUNK;
    const float* p2 = x + ((size_t)b*NN + n2)*DD + (size_t)ch*CHUNK;
    int t = threadIdx.x;
    float s0 = 0.f, s1 = 0.f, s2 = 0.f;
    #pragma unroll
    for (int i = 0; i < CHUNK/1024; ++i) {
        int off = i*1024 + t*4;
        float4 a = *(const float4*)(p0 + off);
        float4 u = *(const float4*)(p1 + off);
        float4 v = *(const float4*)(p2 + off);
        s0 += a.x*a.x + a.y*a.y + a.z*a.z + a.w*a.w;
        s1 += a.x*u.x + a.y*u.y + a.z*u.z + a.w*u.w;
        s2 += a.x*v.x + a.y*v.y + a.z*v.z + a.w*v.w;
    }
    for (int o = 32; o > 0; o >>= 1) {
        s0 += __shfl_down(s0, o);
        s1 += __shfl_down(s1, o);
        s2 += __shfl_down(s2, o);
    }
    __shared__ float red[4][3];
    int w = t >> 6, l = t & 63;
    if (l == 0) { red[w][0] = s0; red[w][1] = s1; red[w][2] = s2; }
    __syncthreads();
    if (t == 0) {
        float r0 = 0.f, r1 = 0.f, r2 = 0.f;
        for (int i = 0; i < 4; ++i) { r0 += red[i][0]; r1 += red[i][1]; r2 += red[i][2]; }
        float* o = part + ((size_t)bn*CHK + ch)*3;
        o[0] = r0; o[1] = r1; o[2] = r2;
    }
}

// ---------------- Kernel 2: softmax -> combination coefficients ----------------
__global__ void k_coef(const float* __restrict__ part,
                       const float* __restrict__ pos_dec,
                       const float* __restrict__ len_dec,
                       float* __restrict__ coef) {
    int bn = threadIdx.x;
    if (bn >= BB*NN) return;
    int n = bn % NN;
    float d0 = 0.f, d1 = 0.f, d2 = 0.f;
    const float* p = part + (size_t)bn*CHK*3;
    for (int i = 0; i < CHK; ++i) { d0 += p[i*3]; d1 += p[i*3+1]; d2 += p[i*3+2]; }
    float pd = pos_dec[n], ld = len_dec[n];
    float l0 = (1.f - pd)*d0 + pd*d1;
    float l1 = ld*((1.f - pd)*d1 + pd*d2);
    float m  = fmaxf(l0, l1);
    float e0 = expf(l0 - m), e1 = expf(l1 - m);
    float inv = 1.f/(e0 + e1);
    float a0 = e0*inv, a1 = e1*inv;
    coef[bn*3+0] = a0*(1.f - pd);
    coef[bn*3+1] = a0*pd + a1*ld*(1.f - pd);
    coef[bn*3+2] = a1*ld*pd;
}

// ---------------- Kernel 3: conv_w fp32 -> bf16 ----------------
__global__ __launch_bounds__(256) void k_wconv(const float* __restrict__ w,
                                               ushort* __restrict__ wb) {
    int i = blockIdx.x*blockDim.x + threadIdx.x;
    size_t idx = (size_t)i*4;
    if (idx >= (size_t)NC*NC) return;
    float4 a = *(const float4*)(w + idx);
    ushort4 o;
    o.x = f2bf(a.x); o.y = f2bf(a.y); o.z = f2bf(a.z); o.w = f2bf(a.w);
    *(ushort4*)(wb + idx) = o;
}

// ---------------- Kernel 4: featT[b][hw][c] bf16 (transposed combo) ----------------
__global__ __launch_bounds__(256) void k_feat(const float* __restrict__ x,
                                              const float* __restrict__ coef,
                                              ushort* __restrict__ featT) {
    __shared__ float tile[32*129];
    int hwt = blockIdx.x;         // 0..71
    int n   = blockIdx.y;         // 0..9
    int b   = blockIdx.z;         // 0..15
    int bn  = b*NN + n;
    float c0 = coef[bn*3+0], c1 = coef[bn*3+1], c2 = coef[bn*3+2];
    int n1 = (n + 1) % NN, n2 = (n + 2) % NN;
    const float* p0 = x + ((size_t)b*NN + n )*DD;
    const float* p1 = x + ((size_t)b*NN + n1)*DD;
    const float* p2 = x + ((size_t)b*NN + n2)*DD;
    int t = threadIdx.x;
    int hw0 = hwt*32;

    int ccl = t >> 3;             // 0..31
    int hwi = (t & 7) * 4;        // 0..28
    #pragma unroll
    for (int p = 0; p < 4; ++p) {
        int cc = p*32 + ccl;
        size_t off = (size_t)cc*HWD + hw0 + hwi;
        float4 a = *(const float4*)(p0 + off);
        float4 u = *(const float4*)(p1 + off);
        float4 v = *(const float4*)(p2 + off);
        tile[(hwi+0)*129 + cc] = c0*a.x + c1*u.x + c2*v.x;
        tile[(hwi+1)*129 + cc] = c0*a.y + c1*u.y + c2*v.y;
        tile[(hwi+2)*129 + cc] = c0*a.z + c1*u.z + c2*v.z;
        tile[(hwi+3)*129 + cc] = c0*a.w + c1*u.w + c2*v.w;
    }
    __syncthreads();

    int hwl = t >> 4;             // 0..15
    int cc0 = (t & 15) * 8;       // 0..120
    #pragma unroll
    for (int p = 0; p < 2; ++p) {
        int hw = p*16 + hwl;
        const float* src = &tile[hw*129 + cc0];
        union { ushort us[8]; uint4 v; } pk;
        #pragma unroll
        for (int j = 0; j < 8; ++j) pk.us[j] = f2bf(src[j]);
        ushort* dst = featT + (size_t)b*HWD*NC + (size_t)(hw0 + hw)*NC + n*CC + cc0;
        *(uint4*)dst = pk.v;
    }
}

// ---------------- Kernel 5: 256x256 GEMM, half-K-tile 4-slot ring, 8-phase/K-tile ----------------
// LDS per half-slot: [256 rows][4 chunks of 16B], physical chunk = logical ^ ((row>>1)&3)
// (R2-verified zero-conflict involution). gload_lds dest stays linear; global source
// pre-swizzled. Counted vmcnt(8): halves ht+2, ht+3 stay in flight across barriers.
__global__ __launch_bounds__(512, 2) void k_gemm(const ushort* __restrict__ Wb,
                                                 const ushort* __restrict__ featT,
                                                 const float* __restrict__ bias,
                                                 const float* __restrict__ x,
                                                 float* __restrict__ out) {
    __shared__ ushort S[4][2][BM*BK2];   // [slot][A=0/B=1][256*32] = 128 KiB

    // bijective XCD swizzle: 720 blocks, 90/XCD; the 5 o-tiles sharing a featT
    // panel stay on one XCD's L2.
    int bid = blockIdx.x;
    int wkid = (bid & 7) * 90 + (bid >> 3);
    int b   = wkid / 45;
    int r45 = wkid % 45;
    int hwt = r45 / 5;
    int ot  = r45 % 5;
    int o0 = ot*BM, hw0 = hwt*BN;

    int t = threadIdx.x;
    int l = t & 63;
    int w = t >> 6;
    int wr = w >> 2, wc = w & 3;      // 2 x 4 wave grid

    const ushort* Ag = Wb + (size_t)o0*NC;
    const ushort* Bg = featT + (size_t)b*HWD*NC + (size_t)hw0*NC;

    // staging: 1024 16B-slots per operand-half; thread t covers slots t and t+512
    int sl0 = t, sl1 = 512 + t;
    int sr0 = sl0 >> 2, sc0 = sl0 & 3;
    int sr1 = sl1 >> 2, sc1 = sl1 & 3;
    size_t ga0 = (size_t)sr0*NC + (size_t)((sc0 ^ ((sr0 >> 1) & 3)) * 8);
    size_t ga1 = (size_t)sr1*NC + (size_t)((sc1 ^ ((sr1 >> 1) & 3)) * 8);

#define STAGE_A(ht_) do { ushort* d_ = &S[(ht_)&3][0][0]; size_t ko_ = (size_t)(ht_)*BK2; \
    gload_lds16(Ag + ga0 + ko_, d_ + sl0*8); \
    gload_lds16(Ag + ga1 + ko_, d_ + sl1*8); } while(0)
#define STAGE_B(ht_) do { ushort* d_ = &S[(ht_)&3][1][0]; size_t ko_ = (size_t)(ht_)*BK2; \
    gload_lds16(Bg + ga0 + ko_, d_ + sl0*8); \
    gload_lds16(Bg + ga1 + ko_, d_ + sl1*8); } while(0)

    // fragment read offsets
    int rowA0 = wr*128 + (l & 15);                 // + mq*64 + i*16
    int rowB0 = wc*64  + (l & 15);                 // + n*16
    int ksw   = ((l >> 4) ^ ((l >> 1) & 3)) * 8;   // swizzled 16B chunk (ushort idx)

    f32x4 acc[8][4] = {};

    // prologue: stage halves 0,1,2 (12 loads); wait half 0 (8 remain in flight)
    STAGE_A(0); STAGE_B(0);
    STAGE_A(1); STAGE_B(1);
    STAGE_A(2); STAGE_B(2);
    asm volatile("s_waitcnt vmcnt(8)" ::: "memory");
    __builtin_amdgcn_s_barrier();
    __builtin_amdgcn_sched_barrier(0);

    for (int ht = 0; ht < NHALF; ++ht) {
        const ushort* as = &S[ht & 3][0][0];
        const ushort* bs = &S[ht & 3][1][0];

        // ---- phase 1: B frags + A lower half; stage A of half ht+3 ----
        bf16x8 bfr[4], af0[4], af1[4];
        #pragma unroll
        for (int n = 0; n < 4; ++n)
            bfr[n] = *(const bf16x8*)&bs[(rowB0 + n*16)*BK2 + ksw];
        #pragma unroll
        for (int i = 0; i < 4; ++i)
            af0[i] = *(const bf16x8*)&as[(rowA0 + i*16)*BK2 + ksw];
        if (ht + 3 < NHALF) STAGE_A(ht + 3);
        __builtin_amdgcn_s_barrier();
        __builtin_amdgcn_sched_barrier(0);
        __builtin_amdgcn_s_setprio(1);
        #pragma unroll
        for (int i = 0; i < 4; ++i)
            #pragma unroll
            for (int n = 0; n < 4; ++n)
                acc[i][n] = __builtin_amdgcn_mfma_f32_16x16x32_bf16(af0[i], bfr[n], acc[i][n], 0, 0, 0);
        __builtin_amdgcn_s_setprio(0);
        __builtin_amdgcn_s_barrier();
        __builtin_amdgcn_sched_barrier(0);

        // ---- phase 2: A upper half; stage B of half ht+3; counted vmcnt ----
        #pragma unroll
        for (int i = 0; i < 4; ++i)
            af1[i] = *(const bf16x8*)&as[(rowA0 + 64 + i*16)*BK2 + ksw];
        if (ht + 3 < NHALF) STAGE_B(ht + 3);
        if (ht < NHALF - 3)       asm volatile("s_waitcnt vmcnt(8)" ::: "memory");
        else if (ht == NHALF - 3) asm volatile("s_waitcnt vmcnt(4)" ::: "memory");
        else if (ht == NHALF - 2) asm volatile("s_waitcnt vmcnt(0)" ::: "memory");
        __builtin_amdgcn_s_barrier();
        __builtin_amdgcn_sched_barrier(0);
        __builtin_amdgcn_s_setprio(1);
        #pragma unroll
        for (int i = 0; i < 4; ++i)
            #pragma unroll
            for (int n = 0; n < 4; ++n)
                acc[4+i][n] = __builtin_amdgcn_mfma_f32_16x16x32_bf16(af1[i], bfr[n], acc[4+i][n], 0, 0, 0);
        __builtin_amdgcn_s_setprio(0);
        __builtin_amdgcn_s_barrier();
        __builtin_amdgcn_sched_barrier(0);
    }
#undef STAGE_A
#undef STAGE_B

    // epilogue: + bias + residual x
    #pragma unroll
    for (int m = 0; m < 8; ++m) {
        int ro_base = o0 + wr*128 + m*16 + ((l >> 4) << 2);
        #pragma unroll
        for (int n = 0; n < 4; ++n) {
            int col = hw0 + wc*64 + n*16 + (l & 15);
            #pragma unroll
            for (int r = 0; r < 4; ++r) {
                int ro = ro_base + r;
                size_t idx = (size_t)b*NC*HWD + (size_t)ro*HWD + col;
                out[idx] = acc[m][n][r] + bias[ro] + x[idx];
            }
        }
    }
}

extern "C" void kernel_launch(void* const* d_in, const int* in_sizes, int n_in,
                              void* d_out, int out_size, void* d_ws, size_t ws_size,
                              hipStream_t stream) {
    const float* x       = (const float*)d_in[0];
    const float* pos_dec = (const float*)d_in[1];
    const float* len_dec = (const float*)d_in[2];
    const float* conv_w  = (const float*)d_in[3];
    const float* conv_b  = (const float*)d_in[4];
    float* out = (float*)d_out;

    char* ws = (char*)d_ws;
    ushort* featT = (ushort*)ws;                                   // 94,371,840 B
    ushort* wb    = (ushort*)(ws + FEAT_BYTES);                    // 3,276,800 B
    float*  part  = (float*)(ws + FEAT_BYTES + WB_BYTES);          // 69,120 B
    float*  coef  = part + PART_FLOATS;                            // 1,920 B

    k_dots <<<dim3(BB*NN*CHK), 256, 0, stream>>>(x, part);
    k_coef <<<dim3(1), 256, 0, stream>>>(part, pos_dec, len_dec, coef);
    k_wconv<<<dim3(1600), 256, 0, stream>>>(conv_w, wb);
    k_feat <<<dim3(72, NN, BB), 256, 0, stream>>>(x, coef, featT);
    k_gemm <<<dim3(720), 512, 0, stream>>>(wb, featT, conv_b, x, out);
}